// Round 1
// baseline (508.029 us; speedup 1.0000x reference)
//
#include <hip/hip_runtime.h>

// Correlation cost volume as a banded bf16 MFMA GEMM.
//   out[b,i,h,x] = (1/256) * sum_c L[b,c,h,x] * R[b,c,h,x-i],  x>=i, else 0.
//
// v2: occupancy-focused restructure.
//  - Half-row blocks: grid = 1440, block = (b, h, xh) covering x in [160*xh, 160*xh+160).
//    320 threads = 5 waves; wave w owns x-tiles {2w, 2w+1} (local) -> acc[2][5] = 40 f32
//    (was 80). Total VGPR+AGPR target <= 128 so 3 blocks (15 waves)/CU fit
//    (previous version: acc 80 + 68 VGPR ~ 148 -> 8-wave cap -> 1 block/CU, 13.7% occ).
//  - LDS: L 160 cols + R 224 cols (64-col left halo), RSTR=20 pad (2-way banks = free).
//  - Register prefetch: chunk k+1's 10 float4 global loads are issued right after the
//    post-staging barrier so they overlap fragment reads + 10 MFMAs + the next barrier.

typedef short bf16x8 __attribute__((ext_vector_type(8)));
typedef float f32x4 __attribute__((ext_vector_type(4)));

#define Bb 4
#define Cc 256
#define Hh 180
#define Ww 320
#define MAXD 64
#define KC 32            // channels per K-chunk
#define NCHUNK (Cc / KC) // 8
#define RSTR 20          // dwords per x-row in LDS (16 data + 4 pad)
#define HW (Hh * Ww)
#define LROWS 160        // L columns staged per block
#define RROWS 224        // R columns staged per block (64-col halo)

// pack two floats to packed bf16 (lo=a, hi=b), round-to-nearest-even
__device__ __forceinline__ unsigned int bf16rne2(float a, float b) {
    unsigned int ua = __float_as_uint(a);
    unsigned int ub = __float_as_uint(b);
    ua = (ua + 0x7FFFu + ((ua >> 16) & 1u)) >> 16;
    ub = (ub + 0x7FFFu + ((ub >> 16) & 1u)) & 0xFFFF0000u;
    return ua | ub;
}

__global__ __launch_bounds__(320, 4)
void _AA_CostVolume_63668595196248_kernel(const float* __restrict__ L,
                                          const float* __restrict__ R,
                                          float* __restrict__ out) {
    __shared__ unsigned int sL[LROWS * RSTR];   // 12800 B
    __shared__ unsigned int sR[RROWS * RSTR];   // 17920 B  (total 30720 B)

    const int tid = threadIdx.x;
    const int bi  = blockIdx.x;
    const int xh  = bi & 1;          // which x-half
    const int rid = bi >> 1;
    const int b   = rid / Hh;
    const int h   = rid % Hh;
    const int X0  = xh * 160;

    // zero-fill invalid outputs (x < i): all have x < 63 < 160, so xh==0 blocks only
    if (xh == 0) {
        const int ob = (b * MAXD * Hh + h) * Ww;
        for (int z = tid; z < MAXD * MAXD; z += 320) {
            const int i = z >> 6;
            const int x = z & 63;
            if (x < i) out[ob + i * HW + x] = 0.0f;
        }
    }

    const int lane = tid & 63;
    const int w    = tid >> 6;      // wave id 0..4
    const int q    = lane >> 4;     // quad 0..3
    const int n    = lane & 15;     // fragment row/col index

    // staging decomposition: cp = channel-pair (dword col), tq -> x quad
    const int cp = tid & 15;
    const int tq = tid >> 4;        // 0..19

    const float* baseL = L + (b * Cc + 2 * cp) * HW + h * Ww + X0;
    const float* baseR = R + (b * Cc + 2 * cp) * HW + h * Ww + X0 - 64;

    // R quad-batch predicates: batch0 rows [0,80) need gx>=0 (xh==0: gx=4tq-64),
    // batch2 rows [160,224) exist only for tq<16. Skipped rows are never read
    // (xh==0 skips y-tiles lu<4, i.e. rows <64).
    const bool rv0 = (xh != 0) || (tq >= 16);
    const bool rv2 = (tq < 16);

    const int frag_off = n * RSTR + 4 * q;  // dword offset within a 16-row tile
    const int luMin = (xh == 0) ? 4 : 0;    // first valid local y-tile

    f32x4 acc[2][5];
#pragma unroll
    for (int xt = 0; xt < 2; ++xt)
#pragma unroll
        for (int du = 0; du < 5; ++du) {
            f32x4 z = {0.f, 0.f, 0.f, 0.f};
            acc[xt][du] = z;
        }

    // prefetch registers: 10 float4 = 40 VGPR live across the MFMA phase
    float4 pl0a, pl0b, pl1a, pl1b;
    float4 pr0a, pr0b, pr1a, pr1b, pr2a, pr2b;

#define LOADCHUNK(KCI) do {                                               \
        const int ko = (KCI) * (KC * HW);                                 \
        pl0a = *(const float4*)(baseL + ko + 4 * tq);                     \
        pl0b = *(const float4*)(baseL + ko + HW + 4 * tq);                \
        pl1a = *(const float4*)(baseL + ko + 4 * (tq + 20));              \
        pl1b = *(const float4*)(baseL + ko + HW + 4 * (tq + 20));         \
        if (rv0) {                                                       \
            pr0a = *(const float4*)(baseR + ko + 4 * tq);                 \
            pr0b = *(const float4*)(baseR + ko + HW + 4 * tq);            \
        }                                                                \
        pr1a = *(const float4*)(baseR + ko + 4 * (tq + 20));              \
        pr1b = *(const float4*)(baseR + ko + HW + 4 * (tq + 20));         \
        if (rv2) {                                                       \
            pr2a = *(const float4*)(baseR + ko + 4 * (tq + 40));          \
            pr2b = *(const float4*)(baseR + ko + HW + 4 * (tq + 40));     \
        }                                                                \
    } while (0)

#define STORE4(SBUF, ROW0, VA, VB) do {                                   \
        const float* _fa = (const float*)&(VA);                           \
        const float* _fb = (const float*)&(VB);                           \
        _Pragma("unroll")                                                 \
        for (int j = 0; j < 4; ++j)                                       \
            SBUF[((ROW0) + j) * RSTR + cp] = bf16rne2(_fa[j], _fb[j]);    \
    } while (0)

    LOADCHUNK(0);

    for (int kc = 0; kc < NCHUNK; ++kc) {
        __syncthreads();   // previous chunk's fragment reads done (LDS free)
        STORE4(sL, 4 * tq, pl0a, pl0b);
        STORE4(sL, 4 * (tq + 20), pl1a, pl1b);
        if (rv0) STORE4(sR, 4 * tq, pr0a, pr0b);
        STORE4(sR, 4 * (tq + 20), pr1a, pr1b);
        if (rv2) STORE4(sR, 4 * (tq + 40), pr2a, pr2b);
        __syncthreads();   // LDS ready

        // issue next chunk's loads NOW: in flight across frag reads + MFMA + barrier
        if (kc + 1 < NCHUNK) LOADCHUNK(kc + 1);

        // A fragments for this wave's 2 x-tiles
        const bf16x8 af0 = *(const bf16x8*)&sL[(16 * (2 * w + 0) + n) * RSTR + 4 * q];
        const bf16x8 af1 = *(const bf16x8*)&sL[(16 * (2 * w + 1) + n) * RSTR + 4 * q];

        // B fragments over the local y-tile window [2w, 2w+5]
#pragma unroll
        for (int uu = 0; uu < 6; ++uu) {
            const int lu = 2 * w + uu;
            if (lu >= luMin) {   // wave-uniform; lu>=4 also implies staged rows valid
                const bf16x8 bfr = *(const bf16x8*)&sR[lu * (16 * RSTR) + frag_off];
                if (uu <= 4)     // xt=0: du = 4-uu
                    acc[0][4 - uu] = __builtin_amdgcn_mfma_f32_16x16x32_bf16(
                        af0, bfr, acc[0][4 - uu], 0, 0, 0);
                if (uu >= 1)     // xt=1: du = 5-uu
                    acc[1][5 - uu] = __builtin_amdgcn_mfma_f32_16x16x32_bf16(
                        af1, bfr, acc[1][5 - uu], 0, 0, 0);
            }
        }
    }

    // epilogue: lane holds D[m = 4q+r][n] of tile (gt, gu = gt-du); i = x - y
    const float sc = 1.0f / 256.0f;
#pragma unroll
    for (int xt = 0; xt < 2; ++xt) {
        const int gt = 10 * xh + 2 * w + xt;
        const int x0 = 16 * gt + 4 * q;
#pragma unroll
        for (int du = 0; du < 5; ++du) {
            if (gt - du >= 0) {   // y-tile valid, wave-uniform
                const int ib = 16 * du + 4 * q - n;
#pragma unroll
                for (int r = 0; r < 4; ++r) {
                    const int i = ib + r;
                    if (i >= 0 && i < MAXD)
                        out[((b * MAXD + i) * Hh + h) * Ww + x0 + r] = acc[xt][du][r] * sc;
                }
            }
        }
    }
#undef LOADCHUNK
#undef STORE4
}

extern "C" void kernel_launch(void* const* d_in, const int* in_sizes, int n_in,
                              void* d_out, int out_size, void* d_ws, size_t ws_size,
                              hipStream_t stream) {
    const float* left  = (const float*)d_in[0];
    const float* right = (const float*)d_in[1];
    float* out = (float*)d_out;
    dim3 grid(2 * Bb * Hh);
    dim3 block(320);
    _AA_CostVolume_63668595196248_kernel<<<grid, block, 0, stream>>>(left, right, out);
}

// Round 2
// 497.800 us; speedup vs baseline: 1.0205x; 1.0205x over previous
//
#include <hip/hip_runtime.h>

// Correlation cost volume as a banded bf16 MFMA GEMM.
//   out[b,i,h,x] = (1/256) * sum_c L[b,c,h,x] * R[b,c,h,x-i],  x>=i, else 0.
//
// v3: coalescing-focused restructure (occupancy was NOT the limiter: v2 raised
// occupancy 1.6x with zero perf change; both v1/v2 pinned at ~1.6 TB/s with
// channel-major lane layout -> 64-line scatter per wave memory op).
//  - Lanes are x-fastest for ALL global traffic: staging loads are 40/56-lane
//    contiguous 640-896B runs; epilogue stores are LDS-transposed f32 rows.
//  - LDS layout flipped to [c-pair][x] dwords (bf16 lo=even ch, hi=odd ch),
//    stride 164 (= 4 mod 32): b128 staging writes along x (volume-floor banks),
//    fragment = 4x ds_read_b32 from rows 4q..4q+3 at col x (2-way = free).
//  - Same banded structure: block = (b,h,xh) half-row, 5 waves, wave owns
//    x-tiles {2w,2w+1}, acc[2][5], register prefetch of chunk k+1.

typedef short bf16x8 __attribute__((ext_vector_type(8)));
typedef float f32x4 __attribute__((ext_vector_type(4)));

#define Bb 4
#define Cc 256
#define Hh 180
#define Ww 320
#define MAXD 64
#define KC 32            // channels per K-chunk
#define NCHUNK (Cc / KC) // 8
#define HW (Hh * Ww)
#define LSTR 164         // sL dwords per cp-row (160 x + 4 pad) ; 164 % 32 = 4
#define RSTR2 228        // sR dwords per cp-row (224 x + 4 pad) ; 228 % 32 = 4
#define EST 164          // epilogue f32 row stride
// LDS: sL 16*164 + sR 16*228 = 6272 dwords = 25088 B ; epilogue 32*164 = 5248 ok

// pack two floats to packed bf16 (lo=a, hi=b), round-to-nearest-even
__device__ __forceinline__ unsigned int bf16rne2(float a, float b) {
    unsigned int ua = __float_as_uint(a);
    unsigned int ub = __float_as_uint(b);
    ua = (ua + 0x7FFFu + ((ua >> 16) & 1u)) >> 16;
    ub = (ub + 0x7FFFu + ((ub >> 16) & 1u)) & 0xFFFF0000u;
    return ua | ub;
}

__device__ __forceinline__ bf16x8 frag_read(const unsigned int* s, int stride,
                                            int q, int col) {
    union { unsigned int d[4]; bf16x8 v; } u;
#pragma unroll
    for (int jj = 0; jj < 4; ++jj) u.d[jj] = s[(4 * q + jj) * stride + col];
    return u.v;
}

__global__ __launch_bounds__(320, 4)
void _AA_CostVolume_63668595196248_kernel(const float* __restrict__ L,
                                          const float* __restrict__ R,
                                          float* __restrict__ out) {
    __shared__ unsigned int smem[6272];
    unsigned int* sL = smem;
    unsigned int* sR = smem + 16 * LSTR;
    float* eps = (float*)smem;

    const int tid = threadIdx.x;
    const int bi  = blockIdx.x;
    const int xh  = bi & 1;          // which x-half
    const int rid = bi >> 1;
    const int b   = rid / Hh;
    const int h   = rid % Hh;
    const int X0  = xh * 160;

    // zero-fill invalid outputs (x < i): all have x < 63 < 160, so xh==0 blocks only
    if (xh == 0) {
        const int ob = (b * MAXD * Hh + h) * Ww;
        for (int z = tid; z < MAXD * MAXD; z += 320) {
            const int i = z >> 6;
            const int x = z & 63;
            if (x < i) out[ob + i * HW + x] = 0.0f;
        }
    }

    const int lane = tid & 63;
    const int w    = tid >> 6;      // wave id 0..4
    const int q    = lane >> 4;     // quad 0..3
    const int n    = lane & 15;     // fragment row/col index

    // ---- staging decomposition (x-fastest lanes) ----
    // L: 16 cp-rows x 40 f4-quads = 640 slots, 2 passes; pass1 = cp+8, same xq.
    const int cpL = tid / 40;       // 0..7
    const int xqL = tid % 40;
    // R: 16 cp-rows x 56 f4-quads = 896 slots, 3 passes (last: tid<256).
    const int cpR0 = tid / 56;
    const int fR0  = tid % 56;
    const int cpR1 = (tid + 320) / 56;
    const int fR1  = (tid + 320) % 56;
    const int cpR2 = (tid + 640) / 56;
    const int fR2  = (tid + 640) % 56;

    const float* Lbase = L + (b * Cc) * HW + h * Ww + X0;
    const float* Rbase = R + (b * Cc) * HW + h * Ww + X0 - 64;

    // R validity: xh==0 skips cols with gx<0 (f<16); those rows are never read
    // (luMin=4 => read cols >= 64). Pass2 exists only for tid<256.
    const bool rvg0 = (xh != 0) || (fR0 >= 16);
    const bool rvg1 = (xh != 0) || (fR1 >= 16);
    const bool rvg2 = (tid < 256) && ((xh != 0) || (fR2 >= 16));

    // LDS write dword offsets (b128-aligned: stride % 4 == 0)
    const int wL0 = cpL * LSTR + 4 * xqL;
    const int wL1 = (cpL + 8) * LSTR + 4 * xqL;
    const int wR0 = cpR0 * RSTR2 + 4 * fR0;
    const int wR1 = cpR1 * RSTR2 + 4 * fR1;
    const int wR2 = cpR2 * RSTR2 + 4 * fR2;

    const int luMin = (xh == 0) ? 4 : 0;    // first valid local y-tile

    f32x4 acc[2][5];
#pragma unroll
    for (int xt = 0; xt < 2; ++xt)
#pragma unroll
        for (int du = 0; du < 5; ++du) {
            f32x4 z = {0.f, 0.f, 0.f, 0.f};
            acc[xt][du] = z;
        }

    // prefetch registers: 10 float4 = 40 VGPR live across the MFMA phase
    float4 pl0a = {0,0,0,0}, pl0b = {0,0,0,0}, pl1a = {0,0,0,0}, pl1b = {0,0,0,0};
    float4 pr0a = {0,0,0,0}, pr0b = {0,0,0,0}, pr1a = {0,0,0,0}, pr1b = {0,0,0,0};
    float4 pr2a = {0,0,0,0}, pr2b = {0,0,0,0};

#define LOADCHUNK(KCI) do {                                                  \
        const float* Lc = Lbase + (KCI) * (KC * HW);                         \
        const float* Rc = Rbase + (KCI) * (KC * HW);                         \
        pl0a = *(const float4*)(Lc + (2 * cpL) * HW + 4 * xqL);              \
        pl0b = *(const float4*)(Lc + (2 * cpL + 1) * HW + 4 * xqL);          \
        pl1a = *(const float4*)(Lc + (2 * cpL + 16) * HW + 4 * xqL);         \
        pl1b = *(const float4*)(Lc + (2 * cpL + 17) * HW + 4 * xqL);         \
        if (rvg0) {                                                          \
            pr0a = *(const float4*)(Rc + (2 * cpR0) * HW + 4 * fR0);         \
            pr0b = *(const float4*)(Rc + (2 * cpR0 + 1) * HW + 4 * fR0);     \
        }                                                                    \
        if (rvg1) {                                                          \
            pr1a = *(const float4*)(Rc + (2 * cpR1) * HW + 4 * fR1);         \
            pr1b = *(const float4*)(Rc + (2 * cpR1 + 1) * HW + 4 * fR1);     \
        }                                                                    \
        if (rvg2) {                                                          \
            pr2a = *(const float4*)(Rc + (2 * cpR2) * HW + 4 * fR2);         \
            pr2b = *(const float4*)(Rc + (2 * cpR2 + 1) * HW + 4 * fR2);     \
        }                                                                    \
    } while (0)

// pack 2 channels x 4 x-positions into 4 dwords, one b128 write along x
#define PACKST(SBUF, WOFF, VA, VB) do {                                      \
        union { unsigned int d[4]; uint4 v4; } _u;                           \
        _u.d[0] = bf16rne2((VA).x, (VB).x);                                  \
        _u.d[1] = bf16rne2((VA).y, (VB).y);                                  \
        _u.d[2] = bf16rne2((VA).z, (VB).z);                                  \
        _u.d[3] = bf16rne2((VA).w, (VB).w);                                  \
        *(uint4*)&SBUF[WOFF] = _u.v4;                                        \
    } while (0)

    LOADCHUNK(0);

    for (int kc = 0; kc < NCHUNK; ++kc) {
        __syncthreads();   // previous chunk's fragment reads done (LDS free)
        PACKST(sL, wL0, pl0a, pl0b);
        PACKST(sL, wL1, pl1a, pl1b);
        if (rvg0) PACKST(sR, wR0, pr0a, pr0b);
        if (rvg1) PACKST(sR, wR1, pr1a, pr1b);
        if (rvg2) PACKST(sR, wR2, pr2a, pr2b);
        __syncthreads();   // LDS ready

        // issue next chunk's loads NOW: in flight across frag reads + MFMA + barrier
        if (kc + 1 < NCHUNK) LOADCHUNK(kc + 1);

        // A fragments for this wave's 2 x-tiles
        const bf16x8 af0 = frag_read(sL, LSTR, q, 16 * (2 * w + 0) + n);
        const bf16x8 af1 = frag_read(sL, LSTR, q, 16 * (2 * w + 1) + n);

        // B fragments over the local y-tile window [2w, 2w+5]
#pragma unroll
        for (int uu = 0; uu < 6; ++uu) {
            const int lu = 2 * w + uu;
            if (lu >= luMin) {   // wave-uniform
                const bf16x8 bfr = frag_read(sR, RSTR2, q, 16 * lu + n);
                if (uu <= 4)     // xt=0: du = 4-uu
                    acc[0][4 - uu] = __builtin_amdgcn_mfma_f32_16x16x32_bf16(
                        af0, bfr, acc[0][4 - uu], 0, 0, 0);
                if (uu >= 1)     // xt=1: du = 5-uu
                    acc[1][5 - uu] = __builtin_amdgcn_mfma_f32_16x16x32_bf16(
                        af1, bfr, acc[1][5 - uu], 0, 0, 0);
            }
        }
    }

    // ---- epilogue: LDS transpose -> coalesced row stores ----
    // lane holds D[m=4q+r][n] of tile (gt, gu=gt-du): x = 16gt+4q+r, i = 16du+4q+r-n.
    // Two rounds of 32 i-rows: scatter acc -> eps[i_loc][x_loc], then drain
    // 8 rows/pass x 4 passes as float4 row stores (40-lane 640B runs).
    const float sc = 1.0f / 256.0f;
    const int til = tid / 40;   // drain row within pass
    const int fd  = tid % 40;   // drain f4-quad

    for (int ihalf = 0; ihalf < 2; ++ihalf) {
        __syncthreads();   // main-loop frag reads / previous drain done
        const int ilo = 32 * ihalf;
#pragma unroll
        for (int xt = 0; xt < 2; ++xt) {
            const int lt = 2 * w + xt;
            const int gt = 10 * xh + lt;
#pragma unroll
            for (int du = 0; du < 5; ++du) {
                if (gt - du >= 0) {   // y-tile valid, wave-uniform
                    const int ib = 16 * du + 4 * q - n;
#pragma unroll
                    for (int r = 0; r < 4; ++r) {
                        const int i = ib + r;
                        if (i >= ilo && i < ilo + 32)
                            eps[(i - ilo) * EST + 16 * lt + 4 * q + r] =
                                acc[xt][du][r] * sc;
                    }
                }
            }
        }
        __syncthreads();   // eps ready
#pragma unroll
        for (int p = 0; p < 4; ++p) {
            const int il = 8 * p + til;
            const int i  = ilo + il;
            const float4 v = *(const float4*)&eps[il * EST + 4 * fd];
            float* op = out + ((b * MAXD + i) * Hh + h) * Ww + X0 + 4 * fd;
            if (xh || 4 * fd >= i) {
                *(float4*)op = v;
            } else {
                const float* vf = (const float*)&v;
#pragma unroll
                for (int e = 0; e < 4; ++e)
                    if (4 * fd + e >= i) op[e] = vf[e];
            }
        }
    }
#undef LOADCHUNK
#undef PACKST
}

extern "C" void kernel_launch(void* const* d_in, const int* in_sizes, int n_in,
                              void* d_out, int out_size, void* d_ws, size_t ws_size,
                              hipStream_t stream) {
    const float* left  = (const float*)d_in[0];
    const float* right = (const float*)d_in[1];
    float* out = (float*)d_out;
    dim3 grid(2 * Bb * Hh);
    dim3 block(320);
    _AA_CostVolume_63668595196248_kernel<<<grid, block, 0, stream>>>(left, right, out);
}